// Round 10
// baseline (121.111 us; speedup 1.0000x reference)
//
#include <hip/hip_runtime.h>
#include <math.h>

// Problem constants
#define B_    256
#define S_    196
#define DIM_  768
#define D4_   192          // DIM/4
#define POOL_ 1024
#define LEN_  8
#define TOPK_ 8

// Output layout (fp32, concatenated flat in return order)
#define RS_OFF     51118080L
#define SIM_OFF    51118081L
#define IDX_OFF    51380225L

// Workspace layout (float offsets)
#define WS_MPART   0L          // 512 * 192 float4 = 393216 floats (half-row col sums)
#define WS_PNORMT  393216L     // 768*1024 transposed = 786432
#define WS_CANDV   1179648L    // 256*32 floats
#define WS_CANDI   1187840L    // 256*32 ints

// ---------------------------------------------------------------------------
// K1: prep. Blocks 0..511: HALF-row copy + per-column partial sums (2/CU
// during the HBM phase for better latency hiding). Block (2b+h) handles
// batch row b, s-range [98h, 98h+98).  Blocks 512..767: pk l2normT.
// ---------------------------------------------------------------------------
__global__ void __launch_bounds__(768) prep_kernel(
        const float4* __restrict__ x4,
        const float4* __restrict__ pk4,
        float4* __restrict__ out4,
        float4* __restrict__ mp4,          // [512][192] float4 partial col sums
        float* __restrict__ pT) {
    __shared__ float4 part[768];
    __shared__ float  wss[12];
    int t = threadIdx.x;   // 0..767
    int bx = blockIdx.x;
    if (bx < 512) {
        int b = bx >> 1, h = bx & 1;
        const float4* xr = x4 + ((long)b * S_ + h * 98) * D4_;   // 98*192=18816 f4
        float4* ow = out4 + ((long)b * 260 + 64 + h * 98) * D4_;
        float4 acc = {0.f, 0.f, 0.f, 0.f};
        // 18816 = 24*768 + 384 ; (t + k*768) % 192 == t % 192
        #pragma unroll 6
        for (int k = 0; k < 24; ++k) {
            int i = t + k * 768;
            float4 v = xr[i];
            acc.x += v.x; acc.y += v.y; acc.z += v.z; acc.w += v.w;
            ow[i] = v;
        }
        if (t < 384) {
            int i = t + 18432;
            float4 v = xr[i];
            acc.x += v.x; acc.y += v.y; acc.z += v.z; acc.w += v.w;
            ow[i] = v;
        }
        part[t] = acc;
        __syncthreads();
        if (t < 192) {
            float4 a = part[t], b1 = part[t + 192], c1 = part[t + 384], d1 = part[t + 576];
            float4 m;
            m.x = a.x + b1.x + c1.x + d1.x;
            m.y = a.y + b1.y + c1.y + d1.y;
            m.z = a.z + b1.z + c1.z + d1.z;
            m.w = a.w + b1.w + c1.w + d1.w;
            mp4[(long)bx * D4_ + t] = m;     // raw half-sum; finalized in K2
        }
    } else {
        int r0 = (bx - 512) * 4;
        int g = t / 192, i = t % 192;   // group 0..3 == waves [3g,3g+2]
        int r = r0 + g;
        float4 v = pk4[(long)r * D4_ + i];
        float ss = v.x * v.x + v.y * v.y + v.z * v.z + v.w * v.w;
        #pragma unroll
        for (int off = 32; off > 0; off >>= 1) ss += __shfl_xor(ss, off);
        if ((t & 63) == 0) wss[t >> 6] = ss;
        __syncthreads();
        float tot = wss[3 * g] + wss[3 * g + 1] + wss[3 * g + 2];
        float sc = 1.0f / sqrtf(fmaxf(tot, 1e-12f));
        int d = i * 4;
        pT[(long)d       * POOL_ + r] = v.x * sc;
        pT[(long)(d + 1) * POOL_ + r] = v.y * sc;
        pT[(long)(d + 2) * POOL_ + r] = v.z * sc;
        pT[(long)(d + 3) * POOL_ + r] = v.w * sc;
    }
}

// ---------------------------------------------------------------------------
// K2: similarity (final values) + per-row-per-quarter top-8 candidates.
// grid = (64 bg, 4 pc), block = 512. Stages 4 rows: mean = (half0+half1)/196,
// l2norm in-block (proven R3 pattern), then proven R7 full-D 8-way-split dot,
// then candidate extraction parallelized over waves 0..3 (one row each).
// ---------------------------------------------------------------------------
__global__ void __launch_bounds__(512) sim_cand_kernel(
        const float4* __restrict__ mp4,
        const float4* __restrict__ pT4,    // [768][256] float4
        float4* __restrict__ sim4,         // [256][256] float4
        float* __restrict__ cand_val,      // [256][4][8]
        int*   __restrict__ cand_idx) {    // [256][4][8]
    __shared__ float4 xs4[768];            // 4 rows x 192 quads, 12 KB
    __shared__ float4 red4[7 * 256];       // 28 KB
    __shared__ float4 simq4[4 * 64];       // 4 KB (row values for cand phase)
    __shared__ float  scale[4];
    int bg = blockIdx.x;     // 0..63
    int pc = blockIdx.y;     // 0..3
    int t  = threadIdx.x;    // 0..511
    int q64 = t & 63;
    int ds  = t >> 6;        // 0..7
    // stage: mean of the two half-sums, /196
    for (int i = t; i < 768; i += 512) {
        int r = i / 192, q = i % 192;
        int row = bg * 4 + r;
        float4 h0 = mp4[(long)(row * 2)     * D4_ + q];
        float4 h1 = mp4[(long)(row * 2 + 1) * D4_ + q];
        float4 m = {(h0.x + h1.x) / 196.f, (h0.y + h1.y) / 196.f,
                    (h0.z + h1.z) / 196.f, (h0.w + h1.w) / 196.f};
        xs4[i] = m;
    }
    __syncthreads();
    // row norms: wave w (w<4) reduces row w
    if (ds < 4) {
        float4 v0 = xs4[ds * 192 + q64];
        float4 v1 = xs4[ds * 192 + 64 + q64];
        float4 v2 = xs4[ds * 192 + 128 + q64];
        float ss = v0.x*v0.x + v0.y*v0.y + v0.z*v0.z + v0.w*v0.w
                 + v1.x*v1.x + v1.y*v1.y + v1.z*v1.z + v1.w*v1.w
                 + v2.x*v2.x + v2.y*v2.y + v2.z*v2.z + v2.w*v2.w;
        #pragma unroll
        for (int off = 32; off > 0; off >>= 1) ss += __shfl_xor(ss, off);
        if (q64 == 0) scale[ds] = 1.0f / sqrtf(fmaxf(ss, 1e-12f));
    }
    __syncthreads();
    for (int i = t; i < 768; i += 512) {
        float sc = scale[i / 192];
        float4 m = xs4[i];
        xs4[i] = {m.x * sc, m.y * sc, m.z * sc, m.w * sc};
    }
    __syncthreads();
    // proven R7 dot: 8-way d-split, LDS-reduced
    float4 a0 = {0,0,0,0}, a1 = {0,0,0,0}, a2 = {0,0,0,0}, a3 = {0,0,0,0};
    const float4* pbase = pT4 + ((long)ds * 96) * 256 + pc * 64 + q64;
    int xq = ds * 24;
    #pragma unroll 3
    for (int q = 0; q < 24; ++q) {
        float4 xa = xs4[xq + q];
        float4 xb = xs4[192 + xq + q];
        float4 xc = xs4[384 + xq + q];
        float4 xd = xs4[576 + xq + q];
        const float* xaf = (const float*)&xa;
        const float* xbf = (const float*)&xb;
        const float* xcf = (const float*)&xc;
        const float* xdf = (const float*)&xd;
        #pragma unroll
        for (int j = 0; j < 4; ++j) {
            float4 w = pbase[(q * 4 + j) * 256];
            a0.x += xaf[j] * w.x; a0.y += xaf[j] * w.y; a0.z += xaf[j] * w.z; a0.w += xaf[j] * w.w;
            a1.x += xbf[j] * w.x; a1.y += xbf[j] * w.y; a1.z += xbf[j] * w.z; a1.w += xbf[j] * w.w;
            a2.x += xcf[j] * w.x; a2.y += xcf[j] * w.y; a2.z += xcf[j] * w.z; a2.w += xcf[j] * w.w;
            a3.x += xdf[j] * w.x; a3.y += xdf[j] * w.y; a3.z += xdf[j] * w.z; a3.w += xdf[j] * w.w;
        }
    }
    if (ds > 0) {
        int s = ds - 1;
        red4[s * 256 +        q64] = a0;
        red4[s * 256 +  64  + q64] = a1;
        red4[s * 256 + 128  + q64] = a2;
        red4[s * 256 + 192  + q64] = a3;
    }
    __syncthreads();
    if (ds == 0) {
        #pragma unroll
        for (int s = 0; s < 7; ++s) {
            float4 b0 = red4[s * 256 +       q64];
            float4 b1 = red4[s * 256 +  64 + q64];
            float4 b2 = red4[s * 256 + 128 + q64];
            float4 b3 = red4[s * 256 + 192 + q64];
            a0.x += b0.x; a0.y += b0.y; a0.z += b0.z; a0.w += b0.w;
            a1.x += b1.x; a1.y += b1.y; a1.z += b1.z; a1.w += b1.w;
            a2.x += b2.x; a2.y += b2.y; a2.z += b2.z; a2.w += b2.w;
            a3.x += b3.x; a3.y += b3.y; a3.z += b3.z; a3.w += b3.w;
        }
        long base = ((long)(bg * 4)) * 256 + pc * 64 + q64;
        sim4[base]       = a0;
        sim4[base + 256] = a1;
        sim4[base + 512] = a2;
        sim4[base + 768] = a3;
        simq4[q64]       = a0;
        simq4[64 + q64]  = a1;
        simq4[128 + q64] = a2;
        simq4[192 + q64] = a3;
    }
    __syncthreads();
    // candidates: wave w (w<4) extracts row w's quarter top-8
    if (ds < 4) {
        int lane = q64;
        float4 av = simq4[ds * 64 + lane];
        float v0 = av.x, v1 = av.y, v2 = av.z, v3 = av.w;
        int row = bg * 4 + ds;
        int base_idx = pc * 256 + lane * 4;
        for (int it = 0; it < TOPK_; ++it) {
            float bv = v0; int bj = 0;
            if (v1 > bv) { bv = v1; bj = 1; }
            if (v2 > bv) { bv = v2; bj = 2; }
            if (v3 > bv) { bv = v3; bj = 3; }
            int bi = base_idx + bj;
            #pragma unroll
            for (int off = 32; off > 0; off >>= 1) {
                float ov = __shfl_xor(bv, off);
                int   oi = __shfl_xor(bi, off);
                if (ov > bv || (ov == bv && oi < bi)) { bv = ov; bi = oi; }
            }
            if (lane == 0) {
                cand_val[row * 32 + pc * 8 + it] = bv;
                cand_idx[row * 32 + pc * 8 + it] = bi;
            }
            bool mine = (((bi >> 2) & 63) == lane);
            int  mj   = bi & 3;
            v0 = (mine && mj == 0) ? -INFINITY : v0;
            v1 = (mine && mj == 1) ? -INFINITY : v1;
            v2 = (mine && mj == 2) ? -INFINITY : v2;
            v3 = (mine && mj == 3) ? -INFINITY : v3;
        }
    }
}

// ---------------------------------------------------------------------------
// K3: merge + consensus + gather. 256 blocks x 1024 threads, block b -> row b.
// LDS-resident candidate table; thread r<256 does a scalar 4-way sorted-list
// merge (8 steps, no shuffles) -> 8 LDS hist atomics. Then the proven R9
// machinery: one-wave count-top-8, block-0 idx/reduce_sim, contiguous gather.
// ---------------------------------------------------------------------------
__global__ void __launch_bounds__(1024) final_kernel(
        const float4* __restrict__ cand_val4,
        const int4*   __restrict__ cand_idx4,
        const float*  __restrict__ sim,
        const float4* __restrict__ prompt4,
        float4* __restrict__ out4,
        float*  __restrict__ idx_out,
        float*  __restrict__ rs_out) {
    __shared__ float lds_cv[B_ * 32];   // 32 KB
    __shared__ int   lds_ci[B_ * 32];   // 32 KB
    __shared__ int   hist[POOL_];       // 4 KB
    __shared__ int   majs[TOPK_];
    __shared__ float redc[256];
    const int b = blockIdx.x;
    const int t = threadIdx.x;

    // load candidate table + zero hist
    ((float4*)lds_cv)[t]        = cand_val4[t];
    ((float4*)lds_cv)[t + 1024] = cand_val4[t + 1024];
    ((int4*)lds_ci)[t]          = cand_idx4[t];
    ((int4*)lds_ci)[t + 1024]   = cand_idx4[t + 1024];
    hist[t] = 0;
    __syncthreads();

    // merge: thread r handles row r (scalar, shuffle-free)
    if (t < B_) {
        int base = t * 32;
        int h0 = 0, h1 = 0, h2 = 0, h3 = 0;
        #pragma unroll
        for (int it = 0; it < TOPK_; ++it) {
            float v0 = lds_cv[base + h0];
            float v1 = lds_cv[base + 8 + h1];
            float v2 = lds_cv[base + 16 + h2];
            float v3 = lds_cv[base + 24 + h3];
            // pick max, tie -> smaller quarter (== smaller pool idx)
            float bv = v0; int bq = 0;
            if (v1 > bv) { bv = v1; bq = 1; }
            if (v2 > bv) { bv = v2; bq = 2; }
            if (v3 > bv) { bv = v3; bq = 3; }
            int hsel = (bq == 0) ? h0 : (bq == 1) ? h1 : (bq == 2) ? h2 : h3;
            int widx = lds_ci[base + bq * 8 + hsel];
            h0 += (bq == 0); h1 += (bq == 1); h2 += (bq == 2); h3 += (bq == 3);
            atomicAdd(&hist[widx], 1);
        }
    }
    __syncthreads();

    // count top-8 (wave 0; ties -> smallest pool id)
    if (t < 64) {
        int lane = t;
        int v[16];
        #pragma unroll
        for (int j = 0; j < 16; ++j) v[j] = hist[lane + j * 64];
        for (int it = 0; it < TOPK_; ++it) {
            int bv = v[0];
            int bi = lane;
            #pragma unroll
            for (int j = 1; j < 16; ++j) {
                if (v[j] > bv) { bv = v[j]; bi = lane + j * 64; }
            }
            #pragma unroll
            for (int off = 32; off > 0; off >>= 1) {
                int ov = __shfl_xor(bv, off);
                int oi = __shfl_xor(bi, off);
                if (ov > bv || (ov == bv && oi < bi)) { bv = ov; bi = oi; }
            }
            if (lane == 0) majs[it] = bi;
            if ((bi & 63) == lane) v[bi >> 6] = -1;
        }
    }
    __syncthreads();

    // block 0 extras: idx output + reduce_sim
    if (b == 0) {
        for (int i = t; i < B_ * TOPK_; i += 1024) idx_out[i] = (float)majs[i & 7];
        if (t < 256) {
            float s = 0.f;
            const float* r = sim + (long)t * POOL_;
            #pragma unroll
            for (int k = 0; k < TOPK_; ++k) s += r[majs[k]];
            redc[t] = s;
        }
        __syncthreads();
        for (int off = 128; off > 0; off >>= 1) {
            if (t < off) redc[t] += redc[t + off];
            __syncthreads();
        }
        if (t == 0) *rs_out = redc[0] / (float)B_;
    }

    // gather: contiguous head slice of batch row b
    {
        float4* dst = out4 + (long)b * 260 * D4_;   // 64*192 = 12288 float4
        #pragma unroll 4
        for (int k = 0; k < 12; ++k) {
            int i = t + k * 1024;
            int kl = i / 192;
            int d4 = i % 192;
            int pid = majs[kl >> 3];
            dst[i] = prompt4[((long)pid * LEN_ + (kl & 7)) * D4_ + d4];
        }
    }
}

// ---------------------------------------------------------------------------
extern "C" void kernel_launch(void* const* d_in, const int* in_sizes, int n_in,
                              void* d_out, int out_size, void* d_ws, size_t ws_size,
                              hipStream_t stream) {
    const float4* x4      = (const float4*)d_in[0];
    const float4* prompt4 = (const float4*)d_in[1];
    const float4* pk4     = (const float4*)d_in[2];
    float* out = (float*)d_out;
    float* ws  = (float*)d_ws;

    float4* out4     = (float4*)out;
    float4* mp4      = (float4*)(ws + WS_MPART);
    float*  pT       = ws + WS_PNORMT;
    float*  cand_val = ws + WS_CANDV;
    int*    cand_idx = (int*)(ws + WS_CANDI);
    float*  out_rs   = out + RS_OFF;
    float*  out_sim  = out + SIM_OFF;
    float*  out_idx  = out + IDX_OFF;

    // Node 1: half-row copy + mean partials (2 blocks/CU) ; pk l2normT
    prep_kernel<<<768, 768, 0, stream>>>(x4, pk4, out4, mp4, pT);
    // Node 2: mean finalize + l2norm + similarity + quarter candidates
    dim3 sg(64, 4);
    sim_cand_kernel<<<sg, 512, 0, stream>>>(mp4, (const float4*)pT,
                                            (float4*)out_sim, cand_val, cand_idx);
    // Node 3: light merge + consensus + idx/reduce_sim + gather
    final_kernel<<<B_, 1024, 0, stream>>>((const float4*)cand_val,
                                          (const int4*)cand_idx, out_sim,
                                          prompt4, out4, out_idx, out_rs);
}

// Round 11
// 113.176 us; speedup vs baseline: 1.0701x; 1.0701x over previous
//
#include <hip/hip_runtime.h>
#include <math.h>

// Problem constants
#define B_    256
#define S_    196
#define DIM_  768
#define D4_   192          // DIM/4
#define POOL_ 1024
#define LEN_  8
#define TOPK_ 8

// Output layout (fp32, concatenated flat in return order)
#define RS_OFF     51118080L
#define SIM_OFF    51118081L
#define IDX_OFF    51380225L

// Workspace layout (float offsets)  — proven round-4/round-9 layout
#define WS_XNORM   0L          // 256*768             = 196608
#define WS_PNORMT  196608L     // 768*1024 transposed = 786432
#define WS_PART    983040L     // 4*256*1024 partials = 1048576
#define WS_ROWIDS  2031616L    // 256*8 int

// ---------------------------------------------------------------------------
// Nontemporal float4 helpers (evict-first streaming; no L2 pollution)
// ---------------------------------------------------------------------------
typedef float f4v __attribute__((ext_vector_type(4)));
__device__ __forceinline__ float4 ntload4(const float4* p) {
    f4v v = __builtin_nontemporal_load((const f4v*)p);
    float4 r; r.x = v.x; r.y = v.y; r.z = v.z; r.w = v.w;
    return r;
}
__device__ __forceinline__ void ntstore4(float4* p, float4 v) {
    f4v u; u.x = v.x; u.y = v.y; u.z = v.z; u.w = v.w;
    __builtin_nontemporal_store(u, (f4v*)p);
}

// ---------------------------------------------------------------------------
// K1: fused prep (R9 structure; copy path nontemporal).
// Blocks 0..255: per-batch-row contiguous copy + mean + l2norm.
// Blocks 256..511: prompt_key l2norm -> transposed pnormT (4 rows/block).
// ---------------------------------------------------------------------------
__global__ void __launch_bounds__(768) prep_kernel(
        const float4* __restrict__ x4,
        const float4* __restrict__ pk4,
        float4* __restrict__ out4,
        float4* __restrict__ xnorm4,
        float* __restrict__ pT) {
    __shared__ float4 part[768];
    __shared__ float  sred[192];
    __shared__ float  sscale;
    __shared__ float  wss[12];
    int t = threadIdx.x;   // 0..767
    if (blockIdx.x < B_) {
        int b = blockIdx.x;
        const float4* xr = x4 + (long)b * (S_ * D4_);          // contiguous 588 KB
        float4* ow = out4 + ((long)b * 260 + 64) * D4_;        // contiguous dest
        float4 acc = {0.f, 0.f, 0.f, 0.f};
        // 196*192 = 37632 = 49*768; (t + k*768) % 192 == t % 192
        #pragma unroll 7
        for (int k = 0; k < 49; ++k) {
            int i = t + k * 768;
            float4 v = ntload4(&xr[i]);
            acc.x += v.x; acc.y += v.y; acc.z += v.z; acc.w += v.w;
            ntstore4(&ow[i], v);
        }
        part[t] = acc;
        __syncthreads();
        float4 m = {0.f, 0.f, 0.f, 0.f};
        if (t < 192) {
            float4 a = part[t], b1 = part[t + 192], c1 = part[t + 384], d1 = part[t + 576];
            m.x = (a.x + b1.x + c1.x + d1.x) / 196.f;
            m.y = (a.y + b1.y + c1.y + d1.y) / 196.f;
            m.z = (a.z + b1.z + c1.z + d1.z) / 196.f;
            m.w = (a.w + b1.w + c1.w + d1.w) / 196.f;
            sred[t] = m.x * m.x + m.y * m.y + m.z * m.z + m.w * m.w;
        }
        __syncthreads();
        if (t < 64) {
            float s2 = sred[t] + sred[t + 64] + sred[t + 128];
            #pragma unroll
            for (int off = 32; off > 0; off >>= 1) s2 += __shfl_xor(s2, off);
            if (t == 0) sscale = 1.0f / sqrtf(fmaxf(s2, 1e-12f));
        }
        __syncthreads();
        if (t < 192) {
            float sc = sscale;
            float4 o = {m.x * sc, m.y * sc, m.z * sc, m.w * sc};
            xnorm4[(long)b * D4_ + t] = o;
        }
    } else {
        int r0 = (blockIdx.x - B_) * 4;
        int g = t / 192, i = t % 192;   // group 0..3 == waves [3g,3g+2]
        int r = r0 + g;
        float4 v = pk4[(long)r * D4_ + i];
        float ss = v.x * v.x + v.y * v.y + v.z * v.z + v.w * v.w;
        #pragma unroll
        for (int off = 32; off > 0; off >>= 1) ss += __shfl_xor(ss, off);
        if ((t & 63) == 0) wss[t >> 6] = ss;
        __syncthreads();
        float tot = wss[3 * g] + wss[3 * g + 1] + wss[3 * g + 2];
        float sc = 1.0f / sqrtf(fmaxf(tot, 1e-12f));
        int d = i * 4;
        pT[(long)d       * POOL_ + r] = v.x * sc;
        pT[(long)(d + 1) * POOL_ + r] = v.y * sc;
        pT[(long)(d + 2) * POOL_ + r] = v.z * sc;
        pT[(long)(d + 3) * POOL_ + r] = v.w * sc;
    }
}

// ---------------------------------------------------------------------------
// K2: similarity partials (byte-identical to R4/R9). grid = (64 bg, 4 dc),
// block = 512. Thread owns 4 rows x 4 consecutive cols; 2-way d-split.
// ---------------------------------------------------------------------------
__global__ void __launch_bounds__(512) simpart_kernel(
        const float4* __restrict__ xnorm4,
        const float4* __restrict__ pT4,    // [768][256] float4
        float4* __restrict__ part4) {      // [4dc][256row][256colquad]
    __shared__ float4 xs4[4 * 48];         // [row][48] f4 = 192 d's chunk
    __shared__ float4 red4[4 * 256];       // [row][colquad]
    int bg = blockIdx.x;     // 0..63
    int dc = blockIdx.y;     // 0..3
    int t  = threadIdx.x;    // 0..511
    int p4 = t & 255;        // colquad: cols 4*p4..4*p4+3
    int ds = t >> 8;         // 0/1 half of the d-chunk
    if (t < 192) {
        int r = t / 48, q = t % 48;
        xs4[r * 48 + q] = xnorm4[(long)(bg * 4 + r) * D4_ + dc * 48 + q];
    }
    __syncthreads();
    float4 a0 = {0,0,0,0}, a1 = {0,0,0,0}, a2 = {0,0,0,0}, a3 = {0,0,0,0};
    int qbase = ds * 24;
    const float4* pbase = pT4 + ((long)dc * 192 + ds * 96) * 256 + p4;
    #pragma unroll 2
    for (int q = 0; q < 24; ++q) {
        float4 xa = xs4[qbase + q];
        float4 xb = xs4[48 + qbase + q];
        float4 xc = xs4[96 + qbase + q];
        float4 xd = xs4[144 + qbase + q];
        const float* xaf = (const float*)&xa;
        const float* xbf = (const float*)&xb;
        const float* xcf = (const float*)&xc;
        const float* xdf = (const float*)&xd;
        #pragma unroll
        for (int j = 0; j < 4; ++j) {
            float4 w = pbase[(q * 4 + j) * 256];
            a0.x += xaf[j] * w.x; a0.y += xaf[j] * w.y; a0.z += xaf[j] * w.z; a0.w += xaf[j] * w.w;
            a1.x += xbf[j] * w.x; a1.y += xbf[j] * w.y; a1.z += xbf[j] * w.z; a1.w += xbf[j] * w.w;
            a2.x += xcf[j] * w.x; a2.y += xcf[j] * w.y; a2.z += xcf[j] * w.z; a2.w += xcf[j] * w.w;
            a3.x += xdf[j] * w.x; a3.y += xdf[j] * w.y; a3.z += xdf[j] * w.z; a3.w += xdf[j] * w.w;
        }
    }
    if (ds == 1) {
        red4[p4]       = a0;
        red4[256 + p4] = a1;
        red4[512 + p4] = a2;
        red4[768 + p4] = a3;
    }
    __syncthreads();
    if (ds == 0) {
        float4 b0 = red4[p4], b1 = red4[256 + p4], b2 = red4[512 + p4], b3 = red4[768 + p4];
        a0.x += b0.x; a0.y += b0.y; a0.z += b0.z; a0.w += b0.w;
        a1.x += b1.x; a1.y += b1.y; a1.z += b1.z; a1.w += b1.w;
        a2.x += b2.x; a2.y += b2.y; a2.z += b2.z; a2.w += b2.w;
        a3.x += b3.x; a3.y += b3.y; a3.z += b3.z; a3.w += b3.w;
        long base = ((long)dc * 256 + bg * 4) * 256 + p4;
        part4[base]       = a0;
        part4[base + 256] = a1;
        part4[base + 512] = a2;
        part4[base + 768] = a3;
    }
}

// ---------------------------------------------------------------------------
// K3: sum 4 partials per row -> sim; per-row top-8 (ties -> smallest index).
// grid = 256 (one wave per row). Byte-identical to R4/R9.
// ---------------------------------------------------------------------------
__global__ void topk_sum_kernel(const float* __restrict__ part,
                                float* __restrict__ sim,
                                int* __restrict__ row_ids) {
    int row  = blockIdx.x;
    int lane = threadIdx.x;      // 64
    float v[16];
    #pragma unroll
    for (int j = 0; j < 16; ++j) {
        int p = lane + j * 64;
        float s = part[(long)row * POOL_ + p]
                + part[(long)(256 + row) * POOL_ + p]
                + part[(long)(512 + row) * POOL_ + p]
                + part[(long)(768 + row) * POOL_ + p];
        v[j] = s;
        sim[(long)row * POOL_ + p] = s;
    }
    for (int it = 0; it < TOPK_; ++it) {
        float bv = v[0];
        int   bi = lane;
        #pragma unroll
        for (int j = 1; j < 16; ++j) {
            if (v[j] > bv) { bv = v[j]; bi = lane + j * 64; }  // keep-first => smallest idx
        }
        #pragma unroll
        for (int off = 32; off > 0; off >>= 1) {
            float ov = __shfl_xor(bv, off);
            int   oi = __shfl_xor(bi, off);
            if (ov > bv || (ov == bv && oi < bi)) { bv = ov; bi = oi; }
        }
        if ((bi & 63) == lane) v[bi >> 6] = -INFINITY;
        if (lane == 0) row_ids[row * TOPK_ + it] = bi;
    }
}

// ---------------------------------------------------------------------------
// K4: gather + light redundant consensus (R9 proven; head writes nontemporal).
// 256 blocks x 1024 threads, block b -> batch row b.
// ---------------------------------------------------------------------------
__global__ void __launch_bounds__(1024) gather_consensus_kernel(
        const int*    __restrict__ row_ids,
        const float*  __restrict__ sim,
        const float4* __restrict__ prompt4,
        float4* __restrict__ out4,
        float*  __restrict__ idx_out,
        float*  __restrict__ rs_out) {
    __shared__ int   hist[POOL_];
    __shared__ int   majs[TOPK_];
    __shared__ float redc[256];
    const int b = blockIdx.x;
    const int t = threadIdx.x;

    // ----- histogram (all blocks, redundant, cheap) -----
    hist[t] = 0;
    __syncthreads();
    atomicAdd(&hist[row_ids[t]], 1);
    atomicAdd(&hist[row_ids[t + 1024]], 1);
    __syncthreads();

    // ----- count top-8 (wave 0 only; ties -> smallest pool id) -----
    if (t < 64) {
        int lane = t;
        int v[16];
        #pragma unroll
        for (int j = 0; j < 16; ++j) v[j] = hist[lane + j * 64];
        for (int it = 0; it < TOPK_; ++it) {
            int bv = v[0];
            int bi = lane;
            #pragma unroll
            for (int j = 1; j < 16; ++j) {
                if (v[j] > bv) { bv = v[j]; bi = lane + j * 64; }
            }
            #pragma unroll
            for (int off = 32; off > 0; off >>= 1) {
                int ov = __shfl_xor(bv, off);
                int oi = __shfl_xor(bi, off);
                if (ov > bv || (ov == bv && oi < bi)) { bv = ov; bi = oi; }
            }
            if (lane == 0) majs[it] = bi;
            if ((bi & 63) == lane) v[bi >> 6] = -1;
        }
    }
    __syncthreads();

    // ----- block 0 extras: idx output + reduce_sim -----
    if (b == 0) {
        for (int i = t; i < B_ * TOPK_; i += 1024) idx_out[i] = (float)majs[i & 7];
        if (t < 256) {
            float s = 0.f;
            const float* r = sim + (long)t * POOL_;
            #pragma unroll
            for (int k = 0; k < TOPK_; ++k) s += r[majs[k]];
            redc[t] = s;
        }
        __syncthreads();
        for (int off = 128; off > 0; off >>= 1) {
            if (t < off) redc[t] += redc[t + off];
            __syncthreads();
        }
        if (t == 0) *rs_out = redc[0] / (float)B_;
    }

    // ----- gather: contiguous head slice of batch row b (nt stores) -----
    {
        float4* dst = out4 + (long)b * 260 * D4_;   // 64*192 = 12288 float4
        #pragma unroll 4
        for (int k = 0; k < 12; ++k) {
            int i = t + k * 1024;
            int kl = i / 192;
            int d4 = i % 192;
            int pid = majs[kl >> 3];
            ntstore4(&dst[i], prompt4[((long)pid * LEN_ + (kl & 7)) * D4_ + d4]);
        }
    }
}

// ---------------------------------------------------------------------------
extern "C" void kernel_launch(void* const* d_in, const int* in_sizes, int n_in,
                              void* d_out, int out_size, void* d_ws, size_t ws_size,
                              hipStream_t stream) {
    const float4* x4      = (const float4*)d_in[0];
    const float4* prompt4 = (const float4*)d_in[1];
    const float4* pk4     = (const float4*)d_in[2];
    float* out = (float*)d_out;
    float* ws  = (float*)d_ws;

    float4* out4    = (float4*)out;
    float4* xnorm4  = (float4*)(ws + WS_XNORM);
    float*  pT      = ws + WS_PNORMT;
    float4* part4   = (float4*)(ws + WS_PART);
    int*    row_ids = (int*)(ws + WS_ROWIDS);
    float*  out_rs  = out + RS_OFF;
    float*  out_sim = out + SIM_OFF;
    float*  out_idx = out + IDX_OFF;

    // Node 1: prep (copy+mean+l2norm, pk l2normT) — streaming path nt
    prep_kernel<<<512, 768, 0, stream>>>(x4, pk4, out4, xnorm4, pT);
    // Node 2: similarity partials over the whole chip       [proven R4/R9]
    dim3 sgrid(64, 4);
    simpart_kernel<<<sgrid, 512, 0, stream>>>(xnorm4, (const float4*)pT, part4);
    // Node 3: sum partials + per-row top-8                  [proven R4/R9]
    topk_sum_kernel<<<B_, 64, 0, stream>>>((const float*)part4, out_sim, row_ids);
    // Node 4: light redundant consensus + idx/reduce_sim + gather (nt stores)
    gather_consensus_kernel<<<B_, 1024, 0, stream>>>(row_ids, out_sim, prompt4,
                                                     out4, out_idx, out_rs);
}